// Round 2
// 295.726 us; speedup vs baseline: 1.0582x; 1.0582x over previous
//
#include <hip/hip_runtime.h>
#include <math.h>

// Problem constants (from reference)
#define BB 8
#define SS 4096
#define DD 512
#define HH 512
#define MM (BB*SS)          // 32768 rows

// Scan chunking
constexpr int TCH = 64;              // timesteps per chunk
constexpr int NC  = SS / TCH;        // 64 chunks
constexpr int BH  = BB * HH;         // 4096 channels

// MFMA GEMM tiling
constexpr int BM = 128;              // rows per block (= 2 chunks of 64 s)
constexpr int BN = 64;               // cols per block (per weight matrix)
constexpr int BK = 64;               // k per stage

typedef short  short8  __attribute__((ext_vector_type(8)));
typedef float  float4v __attribute__((ext_vector_type(4)));

__device__ inline unsigned short f2bf(float f) {
    union { float f; unsigned u; } v; v.f = f;
    unsigned r = v.u + 0x7FFF + ((v.u >> 16) & 1);   // RNE
    return (unsigned short)(r >> 16);
}
__device__ inline float bf_lo(unsigned u) {          // low 16 bits -> float
    union { unsigned u; float f; } x; x.u = u << 16; return x.f;
}
__device__ inline float bf_hi(unsigned u) {          // high 16 bits -> float
    union { unsigned u; float f; } x; x.u = u & 0xffff0000u; return x.f;
}
__device__ inline float fast_rcp(float x) {          // v_rcp_f32, ~1ulp(22b)
    return __builtin_amdgcn_rcpf(x);
}

__device__ inline void async_copy16(const void* g, void* l) {
    __builtin_amdgcn_global_load_lds(
        (const __attribute__((address_space(1))) void*)g,
        (__attribute__((address_space(3))) void*)l, 16, 0, 0);
}

// ---------------------------------------------------------------------------
// fp32 -> bf16 conversion for X (8192 blocks) and the 4 weights (4x128 blocks)
// in a single launch.
// ---------------------------------------------------------------------------
__global__ __launch_bounds__(256)
void conv_all(const float* __restrict__ x,
              const float* __restrict__ w0, const float* __restrict__ w1,
              const float* __restrict__ w2, const float* __restrict__ w3,
              short* __restrict__ Xbf, short* __restrict__ Wbf)
{
    constexpr int XBLK = MM * DD / 8 / 256;   // 8192
    constexpr int WBLK = HH * DD / 8 / 256;   // 128
    const int bid = blockIdx.x;
    const float* src; short* dst; size_t base;
    if (bid < XBLK) {
        src = x; dst = Xbf;
        base = ((size_t)bid * 256 + threadIdx.x) * 8;
    } else {
        const int idx  = bid - XBLK;
        const int wsel = idx / WBLK;
        src = (wsel == 0) ? w0 : (wsel == 1) ? w1 : (wsel == 2) ? w2 : w3;
        dst = Wbf + (size_t)wsel * HH * DD;
        base = ((size_t)(idx % WBLK) * 256 + threadIdx.x) * 8;
    }
    float4 a = *(const float4*)(src + base);
    float4 b = *(const float4*)(src + base + 4);
    short8 r;
    r[0] = f2bf(a.x); r[1] = f2bf(a.y); r[2] = f2bf(a.z); r[3] = f2bf(a.w);
    r[4] = f2bf(b.x); r[5] = f2bf(b.y); r[6] = f2bf(b.z); r[7] = f2bf(b.w);
    *(short8*)(dst + base) = r;
}

// ---------------------------------------------------------------------------
// MFMA gate GEMM + fused chunk-summary scan.
//   kz = X[m,:]·Wz[n,:]+bz[n], kh = X[m,:]·Wh[n,:]+bh[n]
//   a = sigmoid(-kz); v = (1-a)*g(kh); AV[m,n] = pack_bf16(v, a)
//
// This revision (vs round-0 baseline):
//  * T2 XOR-swizzle (both-sides, rule #21): global_load_lds destination stays
//    linear; the per-lane GLOBAL source column is pre-swizzled
//    (lcs = 8*((lane&7)^lr)) and the fragment reads XOR their column offset
//    with (col16&7)*8. Kills the 16-way ds_read_b128 bank conflict
//    (row stride 128B == 0 mod 32 banks).
//  * T3-min 2-phase pipeline (catalog recipe, full drains only — no counted
//    vmcnt, no batch-order assumptions): per K-step
//      stage(next buf) -> ds_read+MFMA(cur buf) ->
//      s_waitcnt vmcnt(0) lgkmcnt(0) -> s_barrier.
//    Stage latency hides under the current MFMA block (round 0 drained
//    immediately after staging: zero overlap).
// ---------------------------------------------------------------------------
__global__ __launch_bounds__(256)
void gemm_gate_mfma(const short* __restrict__ Xg, const short* __restrict__ Wz,
                    const float* __restrict__ bz, const short* __restrict__ Wh,
                    const float* __restrict__ bh, unsigned* __restrict__ AV,
                    float2* __restrict__ cAV)
{
    __shared__ char smem[65536];               // 2 x 32KB staging; av tile reuses buf0
    short*    lds    = (short*)smem;
    unsigned* lds_av = (unsigned*)smem;
    constexpr int BUFS = 16384;                // shorts per buffer (32 KB)
    constexpr int ZOFF = BM * BK;              // 8192  (within buffer)
    constexpr int HOFF = ZOFF + BN * BK;       // 12288 (within buffer)
    constexpr int NIT  = DD / BK;              // 8 K-steps

    const int t    = threadIdx.x;
    const int wave = t >> 6;
    const int lane = t & 63;
    const int col16 = lane & 15;
    const int quad  = lane >> 4;
    const int wm = wave >> 1;          // 0/1: which 64-row half
    const int wn = wave & 1;           // 0/1: which 32-col half
    const int m0 = blockIdx.x * BM;
    const int n0 = blockIdx.y * BN;

    float4v accz[4][2], acch[4][2];
    #pragma unroll
    for (int i = 0; i < 4; ++i)
        #pragma unroll
        for (int j = 0; j < 2; ++j) {
            accz[i][j] = (float4v){0.f, 0.f, 0.f, 0.f};
            acch[i][j] = (float4v){0.f, 0.f, 0.f, 0.f};
        }

    const int lr  = lane >> 3;                 // 0..7 row within an 8-row wave-load
    const int lcs = (((lane & 7) ^ lr) * 8);   // PRE-SWIZZLED global col (bf16 units)

    // one stage = 8 async copies / wave (X:4, Wz:2, Wh:2)
    auto stage = [&](int buf, int k0) {
        short* L = lds + buf * BUFS;
        #pragma unroll
        for (int i = 0; i < 4; ++i) {
            const int r0 = wave * 32 + i * 8;
            async_copy16(Xg + (size_t)(m0 + r0 + lr) * DD + k0 + lcs,
                         &L[r0 * BK]);
        }
        #pragma unroll
        for (int i = 0; i < 2; ++i) {
            const int r0 = wave * 16 + i * 8;
            async_copy16(Wz + (size_t)(n0 + r0 + lr) * DD + k0 + lcs,
                         &L[ZOFF + r0 * BK]);
            async_copy16(Wh + (size_t)(n0 + r0 + lr) * DD + k0 + lcs,
                         &L[HOFF + r0 * BK]);
        }
    };

    // prologue: fill buf0, full drain, barrier
    stage(0, 0);
    asm volatile("s_waitcnt vmcnt(0)" ::: "memory");
    __builtin_amdgcn_s_barrier();
    asm volatile("" ::: "memory");

    const int swz = (col16 & 7) * 8;           // read-side XOR (bf16 units)

    #pragma unroll
    for (int it = 0; it < NIT; ++it) {
        // issue next-tile staging first: HBM latency hides under this tile's MFMAs
        if (it + 1 < NIT) stage((it + 1) & 1, (it + 1) * BK);

        const short* L = lds + (it & 1) * BUFS;
        #pragma unroll
        for (int kk = 0; kk < 2; ++kk) {
            const int ko = (kk * 32 + quad * 8) ^ swz;   // swizzled col offset
            short8 af[4], bzf[2], bhf[2];
            #pragma unroll
            for (int mi = 0; mi < 4; ++mi)
                af[mi] = *(const short8*)&L[(wm*64 + mi*16 + col16) * BK + ko];
            #pragma unroll
            for (int nj = 0; nj < 2; ++nj) {
                bzf[nj] = *(const short8*)&L[ZOFF + (wn*32 + nj*16 + col16) * BK + ko];
                bhf[nj] = *(const short8*)&L[HOFF + (wn*32 + nj*16 + col16) * BK + ko];
            }
            #pragma unroll
            for (int mi = 0; mi < 4; ++mi)
                #pragma unroll
                for (int nj = 0; nj < 2; ++nj) {
                    accz[mi][nj] = __builtin_amdgcn_mfma_f32_16x16x32_bf16(af[mi], bzf[nj], accz[mi][nj], 0, 0, 0);
                    acch[mi][nj] = __builtin_amdgcn_mfma_f32_16x16x32_bf16(af[mi], bhf[nj], acch[mi][nj], 0, 0, 0);
                }
        }
        // drain: next-tile stages landed, this tile's ds_reads retired.
        // One barrier per K-step; all waves then agree both buffers are safe.
        asm volatile("s_waitcnt vmcnt(0) lgkmcnt(0)" ::: "memory");
        __builtin_amdgcn_s_barrier();
        asm volatile("" ::: "memory");
    }

    // ---- epilogue: gates -> packed bf16 (v|a) into LDS (buf0 region) ----
    // (last compute read buf1; final barrier passed -> no alias)
    // C/D layout: col=lane&15, row=quad*4+reg (m89/m91-verified)
    // a = rcp(1+exp(kz)); ht = kh>=0 ? kh+0.5 : rcp(1+exp(-kh)); v=(1-a)*ht
    #pragma unroll
    for (int nj = 0; nj < 2; ++nj) {
        const int ln = wn*32 + nj*16 + col16;
        const int n  = n0 + ln;
        const float bzn = bz[n], bhn = bh[n];
        #pragma unroll
        for (int mi = 0; mi < 4; ++mi) {
            const int lmb = wm*64 + mi*16 + quad*4;
            #pragma unroll
            for (int reg = 0; reg < 4; ++reg) {
                const float kz = accz[mi][nj][reg] + bzn;
                const float kh = acch[mi][nj][reg] + bhn;
                const float a  = fast_rcp(1.0f + __expf(kz));       // sigmoid(-kz)
                const float sn = fast_rcp(1.0f + __expf(-kh));      // sigmoid(kh)
                const float ht = (kh >= 0.0f) ? (kh + 0.5f) : sn;
                const float v  = (1.0f - a) * ht;                   // z * h_tilde
                lds_av[(lmb + reg) * 64 + ln] = ((unsigned)f2bf(v) << 16) | f2bf(a);
            }
        }
    }
    __syncthreads();

    // ---- coalesced AV store: 128x64 dwords from LDS, dwordx4/thread ----
    {
        const int row0 = t >> 4;            // 0..15
        const int col  = (t & 15) * 4;      // 0..60
        #pragma unroll
        for (int i = 0; i < 8; ++i) {
            const int row = row0 + i * 16;
            const uint4 u = *(const uint4*)&lds_av[row * 64 + col];
            *(uint4*)&AV[(size_t)(m0 + row) * HH + n0 + col] = u;
        }
    }

    // ---- fused chunk-summary scan: 128 channels x 2 halves = 256 tasks ----
    {
        const int task = t >> 1;            // 0..127: (chunk, column)
        const int hf   = t & 1;             // half of the 64-step chunk
        const int c    = task >> 6;
        const int ln   = task & 63;
        float prod = 1.0f, hl = 0.0f;
        #pragma unroll 8
        for (int s = 0; s < TCH / 2; ++s) {
            const unsigned u = lds_av[(c * TCH + hf * 32 + s) * 64 + ln];
            const float a = bf_lo(u), v = bf_hi(u);
            hl   = fmaf(a, hl, v);
            prod *= a;
        }
        // pair (hf=0: A0,V0 | hf=1: A1,V1); compose: (A0*A1, A1*V0 + V1)
        const float pA = __shfl_xor(prod, 1);
        const float pV = __shfl_xor(hl, 1);
        if (hf == 0) {
            const int b  = m0 >> 12;                    // m0 / 4096
            const int cg = ((m0 & 4095) >> 6) + c;      // global chunk idx
            cAV[(size_t)cg * BH + b * HH + (n0 + ln)] =
                make_float2(prod * pA, fmaf(pA, hl, pV));
        }
    }
}

// ---------------------------------------------------------------------------
// Scan apply (fp32 out, final layer): each (b,c) block computes its own carry
// prefix from the chunk summaries (coalesced, c cheap fmas), then replays its
// chunk. Last-chunk blocks also emit finals (= h at t = S-1).
// ---------------------------------------------------------------------------
__global__ __launch_bounds__(256)
void scan_apply_f32(const unsigned* __restrict__ AV,
                    const float2* __restrict__ cAV,
                    float* __restrict__ out, float* __restrict__ finals)
{
    const int h = blockIdx.x * 256 + threadIdx.x;
    const int b = blockIdx.y;
    const int c = blockIdx.z;
    const int ch = b * HH + h;
    float hcur = 0.5f;                  // h0 = g(0) = 0.5
    for (int cp = 0; cp < c; ++cp) {
        const float2 s = cAV[(size_t)cp * BH + ch];
        hcur = fmaf(s.x, hcur, s.y);
    }
    size_t base = ((size_t)(b * SS + c * TCH)) * HH + h;
    #pragma unroll 8
    for (int tt = 0; tt < TCH; ++tt) {
        const unsigned u = AV[base];
        hcur = fmaf(bf_lo(u), hcur, bf_hi(u));
        out[base] = hcur;
        base += HH;
    }
    if (c == NC - 1) finals[ch] = hcur;
}

// ---------------------------------------------------------------------------
// Scan apply (bf16 out): layer-0 hidden seq feeds only layer-1's GEMM.
// ---------------------------------------------------------------------------
__global__ __launch_bounds__(256)
void scan_apply_bf16(const unsigned* __restrict__ AV,
                     const float2* __restrict__ cAV,
                     short* __restrict__ out, float* __restrict__ finals)
{
    const int h = blockIdx.x * 256 + threadIdx.x;
    const int b = blockIdx.y;
    const int c = blockIdx.z;
    const int ch = b * HH + h;
    float hcur = 0.5f;
    for (int cp = 0; cp < c; ++cp) {
        const float2 s = cAV[(size_t)cp * BH + ch];
        hcur = fmaf(s.x, hcur, s.y);
    }
    size_t base = ((size_t)(b * SS + c * TCH)) * HH + h;
    #pragma unroll 8
    for (int tt = 0; tt < TCH; ++tt) {
        const unsigned u = AV[base];
        hcur = fmaf(bf_lo(u), hcur, bf_hi(u));
        out[base] = (short)f2bf(hcur);
        base += HH;
    }
    if (c == NC - 1) finals[ch] = hcur;
}

// ---------------------------------------------------------------------------
// Orchestration.  ws: AV(64MB) Xbf(32MB) Wbf(2MB) cAV(2MB) ~ 100MB
// ---------------------------------------------------------------------------
extern "C" void kernel_launch(void* const* d_in, const int* in_sizes, int n_in,
                              void* d_out, int out_size, void* d_ws, size_t ws_size,
                              hipStream_t stream)
{
    const float* x   = (const float*)d_in[0];
    const float* wz0 = (const float*)d_in[1];
    const float* bz0 = (const float*)d_in[2];
    const float* wh0 = (const float*)d_in[3];
    const float* bh0 = (const float*)d_in[4];
    const float* wz1 = (const float*)d_in[5];
    const float* bz1 = (const float*)d_in[6];
    const float* wh1 = (const float*)d_in[7];
    const float* bh1 = (const float*)d_in[8];

    float* out    = (float*)d_out;                // (B,S,H) layer-2 hidden seq
    float* finals = out + (size_t)MM * HH;        // (L,B,1,H)

    unsigned* AV  = (unsigned*)d_ws;                      // M*H packed bf16 (v|a)
    short* Xbf    = (short*)(AV + (size_t)MM * HH);       // M*D bf16
    short* Wbf    = Xbf + (size_t)MM * DD;                // 4 * H*D bf16
    float2* cAV   = (float2*)(Wbf + (size_t)4 * HH * DD); // NC*BH float2

    short* Wz0 = Wbf;
    short* Wh0 = Wbf + (size_t)1 * HH * DD;
    short* Wz1 = Wbf + (size_t)2 * HH * DD;
    short* Wh1 = Wbf + (size_t)3 * HH * DD;

    const dim3 gg(MM / BM, HH / BN);       // 256 x 8
    const dim3 gs(HH / 256, BB, NC);       // 2 x 8 x 64

    // ---- conversions (one launch: X + all 4 weights) ----
    conv_all<<<MM * DD / 8 / 256 + 4 * (HH * DD / 8 / 256), 256, 0, stream>>>(
        x, wz0, wh0, wz1, wh1, Xbf, Wbf);

    // ---- layer 0 ----
    gemm_gate_mfma <<<gg, 256, 0, stream>>>(Xbf, Wz0, bz0, Wh0, bh0, AV, cAV);
    scan_apply_bf16<<<gs, 256, 0, stream>>>(AV, cAV, Xbf, finals);            // finals[0]

    // ---- layer 1 ----
    gemm_gate_mfma <<<gg, 256, 0, stream>>>(Xbf, Wz1, bz1, Wh1, bh1, AV, cAV);
    scan_apply_f32 <<<gs, 256, 0, stream>>>(AV, cAV, out, finals + BH);       // finals[1]
}

// Round 4
// 276.613 us; speedup vs baseline: 1.1313x; 1.0691x over previous
//
#include <hip/hip_runtime.h>
#include <math.h>

// Problem constants (from reference)
#define BB 8
#define SS 4096
#define DD 512
#define HH 512
#define MM (BB*SS)          // 32768 rows

// Scan chunking
constexpr int TCH = 64;              // timesteps per chunk
constexpr int NC  = SS / TCH;        // 64 chunks
constexpr int BH  = BB * HH;         // 4096 channels

// MFMA GEMM tiling
constexpr int BM = 128;              // rows per block (= 2 chunks of 64 s)
constexpr int BN = 64;               // cols per block (per weight matrix)
constexpr int BK = 64;               // k per stage

typedef short  short8  __attribute__((ext_vector_type(8)));
typedef float  float4v __attribute__((ext_vector_type(4)));

__device__ inline unsigned short f2bf(float f) {
    union { float f; unsigned u; } v; v.f = f;
    unsigned r = v.u + 0x7FFF + ((v.u >> 16) & 1);   // RNE
    return (unsigned short)(r >> 16);
}
__device__ inline float bf_lo(unsigned u) {          // low 16 bits -> float
    union { unsigned u; float f; } x; x.u = u << 16; return x.f;
}
__device__ inline float bf_hi(unsigned u) {          // high 16 bits -> float
    union { unsigned u; float f; } x; x.u = u & 0xffff0000u; return x.f;
}
__device__ inline float fast_rcp(float x) {          // v_rcp_f32, ~1ulp(22b)
    return __builtin_amdgcn_rcpf(x);
}

__device__ inline void async_copy16(const void* g, void* l) {
    __builtin_amdgcn_global_load_lds(
        (const __attribute__((address_space(1))) void*)g,
        (__attribute__((address_space(3))) void*)l, 16, 0, 0);
}

// ---------------------------------------------------------------------------
// fp32 -> bf16 conversion for X (8192 blocks) and the 4 weights (4x128 blocks)
// in a single launch.
// ---------------------------------------------------------------------------
__global__ __launch_bounds__(256)
void conv_all(const float* __restrict__ x,
              const float* __restrict__ w0, const float* __restrict__ w1,
              const float* __restrict__ w2, const float* __restrict__ w3,
              short* __restrict__ Xbf, short* __restrict__ Wbf)
{
    constexpr int XBLK = MM * DD / 8 / 256;   // 8192
    constexpr int WBLK = HH * DD / 8 / 256;   // 128
    const int bid = blockIdx.x;
    const float* src; short* dst; size_t base;
    if (bid < XBLK) {
        src = x; dst = Xbf;
        base = ((size_t)bid * 256 + threadIdx.x) * 8;
    } else {
        const int idx  = bid - XBLK;
        const int wsel = idx / WBLK;
        src = (wsel == 0) ? w0 : (wsel == 1) ? w1 : (wsel == 2) ? w2 : w3;
        dst = Wbf + (size_t)wsel * HH * DD;
        base = ((size_t)(idx % WBLK) * 256 + threadIdx.x) * 8;
    }
    float4 a = *(const float4*)(src + base);
    float4 b = *(const float4*)(src + base + 4);
    short8 r;
    r[0] = f2bf(a.x); r[1] = f2bf(a.y); r[2] = f2bf(a.z); r[3] = f2bf(a.w);
    r[4] = f2bf(b.x); r[5] = f2bf(b.y); r[6] = f2bf(b.z); r[7] = f2bf(b.w);
    *(short8*)(dst + base) = r;
}

// ---------------------------------------------------------------------------
// MFMA gate GEMM + fused chunk-summary scan.  (round-2 proven version)
//   kz = X[m,:]·Wz[n,:]+bz[n], kh = X[m,:]·Wh[n,:]+bh[n]
//   a = sigmoid(-kz); v = (1-a)*g(kh); AV[m,n] = pack_bf16(v, a)
//
//  * T2 XOR-swizzle (both-sides, rule #21): global_load_lds destination stays
//    linear; the per-lane GLOBAL source column is pre-swizzled
//    (lcs = 8*((lane&7)^lr)) and the fragment reads XOR their column offset
//    with (col16&7)*8. Verified: conflicts 1.36e7 -> 1.05e6.
//  * T3-min 2-phase pipeline, FULL DRAINS ONLY: per K-step
//      stage(next buf) -> ds_read+MFMA(cur buf) ->
//      s_waitcnt vmcnt(0) lgkmcnt(0) -> s_barrier.
//    NOTE: counted-vmcnt (vmcnt(8)) was tried twice (rounds 1,3) and raced
//    both times (absmax 0.43 / 0.047) despite fenced batches — CONDEMNED on
//    this structure. Deep pipelining here requires the full 8-phase template
//    port as an isolated, race-screened change.
// ---------------------------------------------------------------------------
__global__ __launch_bounds__(256)
void gemm_gate_mfma(const short* __restrict__ Xg, const short* __restrict__ Wz,
                    const float* __restrict__ bz, const short* __restrict__ Wh,
                    const float* __restrict__ bh, unsigned* __restrict__ AV,
                    float2* __restrict__ cAV)
{
    __shared__ char smem[65536];               // 2 x 32KB staging; av tile reuses buf0
    short*    lds    = (short*)smem;
    unsigned* lds_av = (unsigned*)smem;
    constexpr int BUFS = 16384;                // shorts per buffer (32 KB)
    constexpr int ZOFF = BM * BK;              // 8192  (within buffer)
    constexpr int HOFF = ZOFF + BN * BK;       // 12288 (within buffer)
    constexpr int NIT  = DD / BK;              // 8 K-steps

    const int t    = threadIdx.x;
    const int wave = t >> 6;
    const int lane = t & 63;
    const int col16 = lane & 15;
    const int quad  = lane >> 4;
    const int wm = wave >> 1;          // 0/1: which 64-row half
    const int wn = wave & 1;           // 0/1: which 32-col half
    const int m0 = blockIdx.x * BM;
    const int n0 = blockIdx.y * BN;

    float4v accz[4][2], acch[4][2];
    #pragma unroll
    for (int i = 0; i < 4; ++i)
        #pragma unroll
        for (int j = 0; j < 2; ++j) {
            accz[i][j] = (float4v){0.f, 0.f, 0.f, 0.f};
            acch[i][j] = (float4v){0.f, 0.f, 0.f, 0.f};
        }

    const int lr  = lane >> 3;                 // 0..7 row within an 8-row wave-load
    const int lcs = (((lane & 7) ^ lr) * 8);   // PRE-SWIZZLED global col (bf16 units)

    // one stage = 8 async copies / wave (X:4, Wz:2, Wh:2)
    auto stage = [&](int buf, int k0) {
        short* L = lds + buf * BUFS;
        #pragma unroll
        for (int i = 0; i < 4; ++i) {
            const int r0 = wave * 32 + i * 8;
            async_copy16(Xg + (size_t)(m0 + r0 + lr) * DD + k0 + lcs,
                         &L[r0 * BK]);
        }
        #pragma unroll
        for (int i = 0; i < 2; ++i) {
            const int r0 = wave * 16 + i * 8;
            async_copy16(Wz + (size_t)(n0 + r0 + lr) * DD + k0 + lcs,
                         &L[ZOFF + r0 * BK]);
            async_copy16(Wh + (size_t)(n0 + r0 + lr) * DD + k0 + lcs,
                         &L[HOFF + r0 * BK]);
        }
    };

    // prologue: fill buf0, full drain, barrier
    stage(0, 0);
    asm volatile("s_waitcnt vmcnt(0)" ::: "memory");
    __builtin_amdgcn_s_barrier();
    asm volatile("" ::: "memory");

    const int swz = (col16 & 7) * 8;           // read-side XOR (bf16 units)

    #pragma unroll
    for (int it = 0; it < NIT; ++it) {
        // issue next-tile staging first: HBM latency hides under this tile's MFMAs
        if (it + 1 < NIT) stage((it + 1) & 1, (it + 1) * BK);

        const short* L = lds + (it & 1) * BUFS;
        #pragma unroll
        for (int kk = 0; kk < 2; ++kk) {
            const int ko = (kk * 32 + quad * 8) ^ swz;   // swizzled col offset
            short8 af[4], bzf[2], bhf[2];
            #pragma unroll
            for (int mi = 0; mi < 4; ++mi)
                af[mi] = *(const short8*)&L[(wm*64 + mi*16 + col16) * BK + ko];
            #pragma unroll
            for (int nj = 0; nj < 2; ++nj) {
                bzf[nj] = *(const short8*)&L[ZOFF + (wn*32 + nj*16 + col16) * BK + ko];
                bhf[nj] = *(const short8*)&L[HOFF + (wn*32 + nj*16 + col16) * BK + ko];
            }
            #pragma unroll
            for (int mi = 0; mi < 4; ++mi)
                #pragma unroll
                for (int nj = 0; nj < 2; ++nj) {
                    accz[mi][nj] = __builtin_amdgcn_mfma_f32_16x16x32_bf16(af[mi], bzf[nj], accz[mi][nj], 0, 0, 0);
                    acch[mi][nj] = __builtin_amdgcn_mfma_f32_16x16x32_bf16(af[mi], bhf[nj], acch[mi][nj], 0, 0, 0);
                }
        }
        // drain: next-tile stages landed, this tile's ds_reads retired.
        asm volatile("s_waitcnt vmcnt(0) lgkmcnt(0)" ::: "memory");
        __builtin_amdgcn_s_barrier();
        asm volatile("" ::: "memory");
    }

    // ---- epilogue: gates -> packed bf16 (v|a) into LDS (buf0 region) ----
    // C/D layout: col=lane&15, row=quad*4+reg (m89/m91-verified)
    // a = rcp(1+exp(kz)); ht = kh>=0 ? kh+0.5 : rcp(1+exp(-kh)); v=(1-a)*ht
    #pragma unroll
    for (int nj = 0; nj < 2; ++nj) {
        const int ln = wn*32 + nj*16 + col16;
        const int n  = n0 + ln;
        const float bzn = bz[n], bhn = bh[n];
        #pragma unroll
        for (int mi = 0; mi < 4; ++mi) {
            const int lmb = wm*64 + mi*16 + quad*4;
            #pragma unroll
            for (int reg = 0; reg < 4; ++reg) {
                const float kz = accz[mi][nj][reg] + bzn;
                const float kh = acch[mi][nj][reg] + bhn;
                const float a  = fast_rcp(1.0f + __expf(kz));       // sigmoid(-kz)
                const float sn = fast_rcp(1.0f + __expf(-kh));      // sigmoid(kh)
                const float ht = (kh >= 0.0f) ? (kh + 0.5f) : sn;
                const float v  = (1.0f - a) * ht;                   // z * h_tilde
                lds_av[(lmb + reg) * 64 + ln] = ((unsigned)f2bf(v) << 16) | f2bf(a);
            }
        }
    }
    __syncthreads();

    // ---- coalesced AV store: 128x64 dwords from LDS, dwordx4/thread ----
    {
        const int row0 = t >> 4;            // 0..15
        const int col  = (t & 15) * 4;      // 0..60
        #pragma unroll
        for (int i = 0; i < 8; ++i) {
            const int row = row0 + i * 16;
            const uint4 u = *(const uint4*)&lds_av[row * 64 + col];
            *(uint4*)&AV[(size_t)(m0 + row) * HH + n0 + col] = u;
        }
    }

    // ---- fused chunk-summary scan: 128 channels x 2 halves = 256 tasks ----
    {
        const int task = t >> 1;            // 0..127: (chunk, column)
        const int hf   = t & 1;             // half of the 64-step chunk
        const int c    = task >> 6;
        const int ln   = task & 63;
        float prod = 1.0f, hl = 0.0f;
        #pragma unroll 8
        for (int s = 0; s < TCH / 2; ++s) {
            const unsigned u = lds_av[(c * TCH + hf * 32 + s) * 64 + ln];
            const float a = bf_lo(u), v = bf_hi(u);
            hl   = fmaf(a, hl, v);
            prod *= a;
        }
        // pair (hf=0: A0,V0 | hf=1: A1,V1); compose: (A0*A1, A1*V0 + V1)
        const float pA = __shfl_xor(prod, 1);
        const float pV = __shfl_xor(hl, 1);
        if (hf == 0) {
            const int b  = m0 >> 12;                    // m0 / 4096
            const int cg = ((m0 & 4095) >> 6) + c;      // global chunk idx
            cAV[(size_t)cg * BH + b * HH + (n0 + ln)] =
                make_float2(prod * pA, fmaf(pA, hl, pV));
        }
    }
}

// ---------------------------------------------------------------------------
// Scan apply (fp32 out, final layer). 1 channel/thread (round-2 config).
// FULL unroll of the 64-step loop: all load addresses are static, so the
// compiler keeps many AV loads in flight instead of the unroll-8
// load/wait/compute duty cycle. `out` is never re-read -> nontemporal store
// (keeps L2 free for AV, which the gemm just wrote).
// ---------------------------------------------------------------------------
__global__ __launch_bounds__(256)
void scan_apply_f32(const unsigned* __restrict__ AV,
                    const float2* __restrict__ cAV,
                    float* __restrict__ out, float* __restrict__ finals)
{
    const int h = blockIdx.x * 256 + threadIdx.x;
    const int b = blockIdx.y;
    const int c = blockIdx.z;
    const int ch = b * HH + h;
    float hcur = 0.5f;                  // h0 = g(0) = 0.5
    #pragma unroll 4
    for (int cp = 0; cp < c; ++cp) {
        const float2 s = cAV[(size_t)cp * BH + ch];
        hcur = fmaf(s.x, hcur, s.y);
    }
    size_t base = ((size_t)(b * SS + c * TCH)) * HH + h;
    #pragma unroll
    for (int tt = 0; tt < TCH; ++tt) {
        const unsigned u = AV[base];
        hcur = fmaf(bf_lo(u), hcur, bf_hi(u));
        __builtin_nontemporal_store(hcur, &out[base]);
        base += HH;
    }
    if (c == NC - 1) finals[ch] = hcur;
}

// ---------------------------------------------------------------------------
// Scan apply (bf16 out): layer-0 hidden seq feeds layer-1's GEMM (Xbf is
// re-read soon -> normal stores, keep it cacheable). Full unroll as above.
// ---------------------------------------------------------------------------
__global__ __launch_bounds__(256)
void scan_apply_bf16(const unsigned* __restrict__ AV,
                     const float2* __restrict__ cAV,
                     short* __restrict__ out, float* __restrict__ finals)
{
    const int h = blockIdx.x * 256 + threadIdx.x;
    const int b = blockIdx.y;
    const int c = blockIdx.z;
    const int ch = b * HH + h;
    float hcur = 0.5f;
    #pragma unroll 4
    for (int cp = 0; cp < c; ++cp) {
        const float2 s = cAV[(size_t)cp * BH + ch];
        hcur = fmaf(s.x, hcur, s.y);
    }
    size_t base = ((size_t)(b * SS + c * TCH)) * HH + h;
    #pragma unroll
    for (int tt = 0; tt < TCH; ++tt) {
        const unsigned u = AV[base];
        hcur = fmaf(bf_lo(u), hcur, bf_hi(u));
        out[base] = (short)f2bf(hcur);
        base += HH;
    }
    if (c == NC - 1) finals[ch] = hcur;
}

// ---------------------------------------------------------------------------
// Orchestration.  ws: AV(64MB) Xbf(32MB) Wbf(2MB) cAV(2MB) ~ 100MB
// ---------------------------------------------------------------------------
extern "C" void kernel_launch(void* const* d_in, const int* in_sizes, int n_in,
                              void* d_out, int out_size, void* d_ws, size_t ws_size,
                              hipStream_t stream)
{
    const float* x   = (const float*)d_in[0];
    const float* wz0 = (const float*)d_in[1];
    const float* bz0 = (const float*)d_in[2];
    const float* wh0 = (const float*)d_in[3];
    const float* bh0 = (const float*)d_in[4];
    const float* wz1 = (const float*)d_in[5];
    const float* bz1 = (const float*)d_in[6];
    const float* wh1 = (const float*)d_in[7];
    const float* bh1 = (const float*)d_in[8];

    float* out    = (float*)d_out;                // (B,S,H) layer-2 hidden seq
    float* finals = out + (size_t)MM * HH;        // (L,B,1,H)

    unsigned* AV  = (unsigned*)d_ws;                      // M*H packed bf16 (v|a)
    short* Xbf    = (short*)(AV + (size_t)MM * HH);       // M*D bf16
    short* Wbf    = Xbf + (size_t)MM * DD;                // 4 * H*D bf16
    float2* cAV   = (float2*)(Wbf + (size_t)4 * HH * DD); // NC*BH float2

    short* Wz0 = Wbf;
    short* Wh0 = Wbf + (size_t)1 * HH * DD;
    short* Wz1 = Wbf + (size_t)2 * HH * DD;
    short* Wh1 = Wbf + (size_t)3 * HH * DD;

    const dim3 gg(MM / BM, HH / BN);       // 256 x 8
    const dim3 gs(HH / 256, BB, NC);       // 2 x 8 x 64 (1 channel/thread)

    // ---- conversions (one launch: X + all 4 weights) ----
    conv_all<<<MM * DD / 8 / 256 + 4 * (HH * DD / 8 / 256), 256, 0, stream>>>(
        x, wz0, wh0, wz1, wh1, Xbf, Wbf);

    // ---- layer 0 ----
    gemm_gate_mfma <<<gg, 256, 0, stream>>>(Xbf, Wz0, bz0, Wh0, bh0, AV, cAV);
    scan_apply_bf16<<<gs, 256, 0, stream>>>(AV, cAV, Xbf, finals);            // finals[0]

    // ---- layer 1 ----
    gemm_gate_mfma <<<gg, 256, 0, stream>>>(Xbf, Wz1, bz1, Wh1, bh1, AV, cAV);
    scan_apply_f32 <<<gs, 256, 0, stream>>>(AV, cAV, out, finals + BH);       // finals[1]
}